// Round 8
// baseline (269.258 us; speedup 1.0000x reference)
//
#include <hip/hip_runtime.h>
#include <hip/hip_bf16.h>
#include <math.h>

#define BB 64
#define NN 256
#define D_VIS 2048
#define D_LBL 512
#define HH 8
#define FF 256
#define DG 2048   // D_GAT = H*F
#define DE 512    // D_EMB
#define ALPHA 0.2f
#define PSTRIDE 264  // Pl row stride in shorts (256 + 8 pad)

using bf16 = __hip_bfloat16;
using short8 = __attribute__((ext_vector_type(8))) short;
using f32x4  = __attribute__((ext_vector_type(4))) float;
__device__ __forceinline__ float b2f(bf16 x) { return __bfloat162float(x); }
__device__ __forceinline__ unsigned short f2bs(float x) {
    bf16 h = __float2bfloat16(x);
    unsigned short u;
    __builtin_memcpy(&u, &h, 2);
    return u;
}

// ---------------- unified bf16-MFMA GEMM with fused epilogues.
// C[MxN] fp32 (+)= A[MxK] fp32 @ W[KxN] fp32 ; optional bf16-transposed store BT[n][m];
// optional per-row head dots: sOut[m*8+h] += sum_col acc*aSrc[col].
// grid (N/64, M/32, zsplit); block 256 (4 waves). Wave w owns cols n0+w*16..+16.
__global__ void __launch_bounds__(256) k_mgemm(const float* __restrict__ A, int lda,
                                               const float* __restrict__ W, int ldw,
                                               float* __restrict__ Cf32, int ldc,
                                               unsigned short* __restrict__ BT,
                                               const float* __restrict__ aSrc,
                                               const float* __restrict__ aDst,
                                               float* __restrict__ sOut,
                                               float* __restrict__ dOut,
                                               int kSlice, int kIters, int atomicC) {
    __shared__ unsigned short As[32][72]; // [m][k] bf16 bits
    __shared__ unsigned short Bs[64][72]; // [n][k] bf16 bits
    const int t = threadIdx.x;
    const int w = t >> 6;
    const int lane = t & 63;
    const int l15 = lane & 15, quad = lane >> 4;
    const int n0 = blockIdx.x * 64;
    const int m0 = blockIdx.y * 32;
    const int kb0 = blockIdx.z * kSlice;

    f32x4 acc[2];
    acc[0] = (f32x4){0.f, 0.f, 0.f, 0.f};
    acc[1] = (f32x4){0.f, 0.f, 0.f, 0.f};

    for (int kc = 0; kc < kIters; ++kc) {
        const int kb = kb0 + kc * 64;
#pragma unroll
        for (int p = 0; p < 2; ++p) {
            const int idx = t + 256 * p;
            const int r = idx >> 4, q4 = idx & 15;
            const float4 v = *(const float4*)(A + (size_t)(m0 + r) * lda + kb + 4 * q4);
            unsigned short s4[4] = {f2bs(v.x), f2bs(v.y), f2bs(v.z), f2bs(v.w)};
            __builtin_memcpy(&As[r][4 * q4], s4, 8);
        }
        {
            const int n = t & 63;
            float bv[16];
#pragma unroll
            for (int i = 0; i < 16; ++i)
                bv[i] = W[(size_t)(kb + w * 16 + i) * ldw + n0 + n];
            unsigned short s8[8];
#pragma unroll
            for (int i = 0; i < 8; ++i) s8[i] = f2bs(bv[i]);
            __builtin_memcpy(&Bs[n][w * 16], s8, 16);
#pragma unroll
            for (int i = 0; i < 8; ++i) s8[i] = f2bs(bv[8 + i]);
            __builtin_memcpy(&Bs[n][w * 16 + 8], s8, 16);
        }
        __syncthreads();
#pragma unroll
        for (int ks = 0; ks < 2; ++ks) {
            const short8 bf = *(const short8*)&Bs[w * 16 + l15][ks * 32 + quad * 8];
#pragma unroll
            for (int mi = 0; mi < 2; ++mi) {
                const short8 af = *(const short8*)&As[mi * 16 + l15][ks * 32 + quad * 8];
                acc[mi] = __builtin_amdgcn_mfma_f32_16x16x32_bf16(af, bf, acc[mi], 0, 0, 0);
            }
        }
        __syncthreads();
    }
    const int col = n0 + w * 16 + l15;
    if (Cf32) {
#pragma unroll
        for (int mi = 0; mi < 2; ++mi)
#pragma unroll
            for (int r = 0; r < 4; ++r) {
                const int row = m0 + mi * 16 + quad * 4 + r;
                if (atomicC) atomicAdd(&Cf32[(size_t)row * ldc + col], acc[mi][r]);
                else Cf32[(size_t)row * ldc + col] = acc[mi][r];
            }
    }
    if (BT) { // bf16 transposed store: BT[col][row]
#pragma unroll
        for (int mi = 0; mi < 2; ++mi) {
            unsigned short s4[4];
#pragma unroll
            for (int r = 0; r < 4; ++r) s4[r] = f2bs(acc[mi][r]);
            __builtin_memcpy(&BT[(size_t)col * NN + m0 + mi * 16 + quad * 4], s4, 8);
        }
    }
    if (sOut) { // head-projection partial dots over this block's 16-col slice
        const float as = aSrc[col];
        const float ad = aDst[col];
        const int h = n0 >> 8; // block fully inside one head (64 | 256)
#pragma unroll
        for (int mi = 0; mi < 2; ++mi)
#pragma unroll
            for (int r = 0; r < 4; ++r) {
                float sv = acc[mi][r] * as;
                float dv = acc[mi][r] * ad;
#pragma unroll
                for (int off = 1; off < 16; off <<= 1) {
                    sv += __shfl_xor(sv, off);
                    dv += __shfl_xor(dv, off);
                }
                if (l15 == 0) {
                    const int row = m0 + mi * 16 + quad * 4 + r;
                    atomicAdd(&sOut[row * HH + h], sv);
                    atomicAdd(&dOut[row * HH + h], dv);
                }
            }
    }
}

// ---------------- init out with bias (fc accumulates atomically into it)
__global__ void __launch_bounds__(256) k_bias(const float* __restrict__ fcb,
                                              float* __restrict__ out) {
    const int i = blockIdx.x * 256 + threadIdx.x;
    out[i] = fcb[i & (DE - 1)];
}

// ---------------- MFMA GAT: softmax(unnorm) + P@W (B-prefetch) + ELU + store + pool dot
// grid (b,h,it) = 64*8*4 blocks, 512 thr (8 waves). Block: rows i0..i0+63, head h.
__global__ void __launch_bounds__(512, 4) k_gat(const unsigned short* __restrict__ WhLbT,
                                                const float* __restrict__ WhV,
                                                const float* __restrict__ srcL,
                                                const float* __restrict__ dstL,
                                                const float* __restrict__ srcV,
                                                const float* __restrict__ dstV,
                                                const float* __restrict__ adj,
                                                const float* __restrict__ pool_q,
                                                bf16* __restrict__ outb,
                                                float* __restrict__ ps) {
    const int bid = blockIdx.x;
    const int it = bid & 3;
    const int h  = (bid >> 2) & 7;
    const int b  = bid >> 5;
    const int i0 = it * 64;
    const int t = threadIdx.x;
    const int w = t >> 6;        // wave 0..7
    const int lane = t & 63;
    const int l15 = lane & 15, quad = lane >> 4;

    __shared__ __align__(16) unsigned short Pl[64][PSTRIDE]; // 33.8 KB
    __shared__ float dls[NN];
    __shared__ float sls[64];
    __shared__ float inv[64];

    if (t < NN) dls[t] = dstL[t * HH + h];
    if (t < 64) sls[t] = srcL[(i0 + t) * HH + h];
    const float c = srcV[b * HH + h] + dstV[b * HH + h];
    // preload epilogue constants early (independent of Pl)
    const int n0 = w * 32;
    float wv[2];
#pragma unroll
    for (int ni = 0; ni < 2; ++ni)
        wv[ni] = WhV[(size_t)b * DG + h * FF + n0 + ni * 16 + l15];
    __syncthreads();

    // ---- phase 1: masked exp (UNNORMALIZED; |e| bounded so no max-sub needed).
    // Wave w: rows w*8..+8 in two passes of 4 rows (16-lane groups).
    {
        const int g = lane >> 4, s = lane & 15;
#pragma unroll
        for (int rr = 0; rr < 2; ++rr) {
            const int iloc = w * 8 + rr * 4 + g;
            const int i = i0 + iloc;
            const float u = c + sls[iloc];
            float pr[16];
            float sum = 0.f;
#pragma unroll
            for (int jj = 0; jj < 8; ++jj) {
                const int j0 = 2 * s + 32 * jj;
                const float2 av = *(const float2*)(adj + (size_t)i * NN + j0);
                float x0 = u + dls[j0];
                float x1 = u + dls[j0 + 1];
                x0 = fmaxf(x0, ALPHA * x0);       // LeakyReLU
                x1 = fmaxf(x1, ALPHA * x1);
                const float p0 = av.x > 0.f ? __expf(x0) : 0.f;
                const float p1 = av.y > 0.f ? __expf(x1) : 0.f;
                pr[2 * jj] = p0; pr[2 * jj + 1] = p1;
                sum += p0 + p1;
            }
#pragma unroll
            for (int off = 1; off < 16; off <<= 1) sum += __shfl_xor(sum, off);
            if (s == 0) inv[iloc] = 1.0f / sum;
#pragma unroll
            for (int jj = 0; jj < 8; ++jj) {
                const unsigned int pk =
                    ((unsigned int)f2bs(pr[2 * jj + 1]) << 16) | f2bs(pr[2 * jj]);
                *(unsigned int*)&Pl[iloc][2 * s + 32 * jj] = pk;
            }
        }
    }
    __syncthreads();

    // ---- phase 2: out[i0:+64, w*32:+32] = P~ @ WhL, B-fragments prefetched 1 kc ahead
    f32x4 acc[4][2];
#pragma unroll
    for (int mi = 0; mi < 4; ++mi)
#pragma unroll
        for (int ni = 0; ni < 2; ++ni) acc[mi][ni] = (f32x4){0.f, 0.f, 0.f, 0.f};

    const unsigned short* wb = WhLbT + (size_t)(h * FF + n0 + l15) * NN + quad * 8;
    short8 bc0 = *(const short8*)(wb);
    short8 bc1 = *(const short8*)(wb + (size_t)16 * NN);
#pragma unroll
    for (int kc = 0; kc < 8; ++kc) {
        short8 bn0, bn1;
        if (kc < 7) {
            bn0 = *(const short8*)(wb + (kc + 1) * 32);
            bn1 = *(const short8*)(wb + (size_t)16 * NN + (kc + 1) * 32);
        }
        short8 a[4];
#pragma unroll
        for (int mi = 0; mi < 4; ++mi)
            a[mi] = *(const short8*)&Pl[mi * 16 + l15][kc * 32 + quad * 8];
#pragma unroll
        for (int mi = 0; mi < 4; ++mi)
            acc[mi][0] = __builtin_amdgcn_mfma_f32_16x16x32_bf16(a[mi], bc0, acc[mi][0], 0, 0, 0);
#pragma unroll
        for (int mi = 0; mi < 4; ++mi)
            acc[mi][1] = __builtin_amdgcn_mfma_f32_16x16x32_bf16(a[mi], bc1, acc[mi][1], 0, 0, 0);
        bc0 = bn0; bc1 = bn1;
    }
    __syncthreads(); // all waves done reading Pl

    // ---- epilogue A: normalize (×inv[row]) + WhV, ELU, bf16 -> Pl[row][f]
#pragma unroll
    for (int mi = 0; mi < 4; ++mi)
#pragma unroll
        for (int r = 0; r < 4; ++r) {
            const int row = mi * 16 + quad * 4 + r;
            const float ivr = inv[row];
#pragma unroll
            for (int ni = 0; ni < 2; ++ni) {
                float x = fmaf(acc[mi][ni][r], ivr, wv[ni]);
                x = x > 0.f ? x : (__expf(x) - 1.0f); // ELU
                Pl[row][n0 + ni * 16 + l15] = f2bs(x);
            }
        }
    __syncthreads();

    // ---- epilogue B: coalesced b128 stores + fused pool-score partial dot
    {
        const int r = t >> 3;        // 0..63
        const int cb = t & 7;        // 0..7
        const int f0 = cb * 32;
        const float* pq = pool_q + h * FF + f0;
        bf16* orow = outb + ((size_t)(b * NN + i0 + r)) * DG + h * FF + f0;
        float dot = 0.f;
#pragma unroll
        for (int i8 = 0; i8 < 4; ++i8) {
            const short8 v = *(const short8*)&Pl[r][f0 + 8 * i8];
            __builtin_memcpy(orow + 8 * i8, &v, 16);
            const float4 q0 = *(const float4*)(pq + 8 * i8);
            const float4 q1 = *(const float4*)(pq + 8 * i8 + 4);
            bf16 bb[8];
            __builtin_memcpy(bb, &v, 16);
            dot = fmaf(b2f(bb[0]), q0.x, dot);
            dot = fmaf(b2f(bb[1]), q0.y, dot);
            dot = fmaf(b2f(bb[2]), q0.z, dot);
            dot = fmaf(b2f(bb[3]), q0.w, dot);
            dot = fmaf(b2f(bb[4]), q1.x, dot);
            dot = fmaf(b2f(bb[5]), q1.y, dot);
            dot = fmaf(b2f(bb[6]), q1.z, dot);
            dot = fmaf(b2f(bb[7]), q1.w, dot);
        }
        dot += __shfl_xor(dot, 1);
        dot += __shfl_xor(dot, 2);
        dot += __shfl_xor(dot, 4);
        if (cb == 0) atomicAdd(&ps[b * NN + i0 + r], dot);
    }
}

// ---------------- pooled[b,:] += sum_{n in tile} softmax(ps)[n] * out[b,n,:]
// grid (4 ntiles, 64 b), 256 thr; thread covers 8 consecutive d via short8 loads.
__global__ void __launch_bounds__(256) k_pool(const bf16* __restrict__ outb,
                                              const float* __restrict__ ps,
                                              float* __restrict__ pooled) {
    const int nt = blockIdx.x;  // 0..3
    const int b  = blockIdx.y;  // 0..63
    const int t  = threadIdx.x;
    __shared__ float wsm[NN];
    __shared__ float redm[4];
    __shared__ float reds[4];
    const float v = ps[b * NN + t];
    float m = v;
#pragma unroll
    for (int off = 32; off; off >>= 1) m = fmaxf(m, __shfl_xor(m, off));
    if ((t & 63) == 0) redm[t >> 6] = m;
    __syncthreads();
    m = fmaxf(fmaxf(redm[0], redm[1]), fmaxf(redm[2], redm[3]));
    const float e = __expf(v - m);
    float s = e;
#pragma unroll
    for (int off = 32; off; off >>= 1) s += __shfl_xor(s, off);
    if ((t & 63) == 0) reds[t >> 6] = s;
    __syncthreads();
    s = reds[0] + reds[1] + reds[2] + reds[3];
    wsm[t] = e / s;
    __syncthreads();
    const int d0 = 8 * t;
    float acc[8];
#pragma unroll
    for (int k = 0; k < 8; ++k) acc[k] = 0.f;
    const bf16* base = outb + (size_t)b * NN * DG + d0;
    for (int n = nt * 64; n < nt * 64 + 64; ++n) {
        const float wn = wsm[n];
        const short8 v8 = *(const short8*)(base + (size_t)n * DG);
        bf16 bb[8];
        __builtin_memcpy(bb, &v8, 16);
#pragma unroll
        for (int k = 0; k < 8; ++k) acc[k] = fmaf(wn, b2f(bb[k]), acc[k]);
    }
#pragma unroll
    for (int k = 0; k < 8; ++k)
        atomicAdd(&pooled[(size_t)b * DG + d0 + k], acc[k]);
}

extern "C" void kernel_launch(void* const* d_in, const int* in_sizes, int n_in,
                              void* d_out, int out_size, void* d_ws, size_t ws_size,
                              hipStream_t stream) {
    (void)in_sizes; (void)n_in; (void)out_size; (void)ws_size;
    const float* visual = (const float*)d_in[0];
    const float* labels = (const float*)d_in[1];
    const float* adj    = (const float*)d_in[2];
    const float* Wg     = (const float*)d_in[3];
    const float* a_src  = (const float*)d_in[4];
    const float* a_dst  = (const float*)d_in[5];
    const float* pool_q = (const float*)d_in[6];
    const float* fcW    = (const float*)d_in[7];
    const float* fcb    = (const float*)d_in[8];
    float* out = (float*)d_out;

    // workspace: [memset region: WhV srcL dstL srcV dstV ps pooled] outb WhLbT
    float* ws_f   = (float*)d_ws;
    float* WhV    = ws_f;                  // 64*2048
    float* srcL   = WhV + BB * DG;         // 256*8
    float* dstL   = srcL + NN * HH;        // 256*8
    float* srcV   = dstL + NN * HH;        // 64*8
    float* dstV   = srcV + BB * HH;        // 64*8
    float* ps     = dstV + BB * HH;        // 64*256
    float* pooled = ps + BB * NN;          // 64*2048
    bf16*  outb   = (bf16*)(pooled + BB * DG);        // 64*256*2048 bf16
    unsigned short* WhLbT = (unsigned short*)(outb + (size_t)BB * NN * DG); // 2048*256

    const size_t zero_floats = (size_t)BB * DG + NN * HH * 2 + BB * HH * 2
                             + (size_t)BB * NN + (size_t)BB * DG;
    hipMemsetAsync(WhV, 0, zero_floats * sizeof(float), stream);
    k_bias<<<BB * DE / 256, 256, 0, stream>>>(fcb, out);

    // WhL GEMM -> bf16 transposed WhLbT + srcL/dstL dots (no fp32 C)
    k_mgemm<<<dim3(DG / 64, NN / 32, 1), 256, 0, stream>>>(
        labels, D_LBL, Wg, DG, nullptr, 0, WhLbT, a_src, a_dst, srcL, dstL,
        D_LBL, D_LBL / 64, 0);
    // WhV GEMM -> fp32 WhV (atomic ksplit z=8) + srcV/dstV dots
    k_mgemm<<<dim3(DG / 64, BB / 32, 8), 256, 0, stream>>>(
        visual, D_VIS, Wg + (size_t)D_LBL * DG, DG, WhV, DG, nullptr,
        a_src, a_dst, srcV, dstV, 256, 4, 1);

    k_gat<<<BB * HH * 4, 512, 0, stream>>>(WhLbT, WhV, srcL, dstL, srcV, dstV,
                                           adj, pool_q, outb, ps);

    k_pool<<<dim3(4, BB), 256, 0, stream>>>(outb, ps, pooled);

    // out = pooled @ fcW + bias: ksplit atomic into bias-init out
    k_mgemm<<<dim3(DE / 64, BB / 32, 8), 256, 0, stream>>>(
        pooled, DG, fcW, DE, out, DE, nullptr, nullptr, nullptr, nullptr, nullptr,
        256, 4, 1);
}

// Round 9
// 245.987 us; speedup vs baseline: 1.0946x; 1.0946x over previous
//
#include <hip/hip_runtime.h>
#include <hip/hip_bf16.h>
#include <math.h>

#define BB 64
#define NN 256
#define D_VIS 2048
#define D_LBL 512
#define HH 8
#define FF 256
#define DG 2048   // D_GAT = H*F
#define DE 512    // D_EMB
#define ALPHA 0.2f
#define PSTRIDE 264  // Pl row stride in shorts (256 + 8 pad)

using bf16 = __hip_bfloat16;
using short8 = __attribute__((ext_vector_type(8))) short;
using f32x4  = __attribute__((ext_vector_type(4))) float;
__device__ __forceinline__ float b2f(bf16 x) { return __bfloat162float(x); }
__device__ __forceinline__ unsigned short f2bs(float x) {
    bf16 h = __float2bfloat16(x);
    unsigned short u;
    __builtin_memcpy(&u, &h, 2);
    return u;
}

// ---------------- unified bf16-MFMA GEMM with fused epilogues.
// grid (N/64, M/32, zsplit); block 256 (4 waves). Wave w owns cols n0+w*16..+16.
__global__ void __launch_bounds__(256) k_mgemm(const float* __restrict__ A, int lda,
                                               const float* __restrict__ W, int ldw,
                                               float* __restrict__ Cf32, int ldc,
                                               unsigned short* __restrict__ BT,
                                               const float* __restrict__ aSrc,
                                               const float* __restrict__ aDst,
                                               float* __restrict__ sOut,
                                               float* __restrict__ dOut,
                                               int kSlice, int kIters, int atomicC) {
    __shared__ unsigned short As[32][72]; // [m][k] bf16 bits
    __shared__ unsigned short Bs[64][72]; // [n][k] bf16 bits
    const int t = threadIdx.x;
    const int w = t >> 6;
    const int lane = t & 63;
    const int l15 = lane & 15, quad = lane >> 4;
    const int n0 = blockIdx.x * 64;
    const int m0 = blockIdx.y * 32;
    const int kb0 = blockIdx.z * kSlice;

    f32x4 acc[2];
    acc[0] = (f32x4){0.f, 0.f, 0.f, 0.f};
    acc[1] = (f32x4){0.f, 0.f, 0.f, 0.f};

    for (int kc = 0; kc < kIters; ++kc) {
        const int kb = kb0 + kc * 64;
#pragma unroll
        for (int p = 0; p < 2; ++p) {
            const int idx = t + 256 * p;
            const int r = idx >> 4, q4 = idx & 15;
            const float4 v = *(const float4*)(A + (size_t)(m0 + r) * lda + kb + 4 * q4);
            unsigned short s4[4] = {f2bs(v.x), f2bs(v.y), f2bs(v.z), f2bs(v.w)};
            __builtin_memcpy(&As[r][4 * q4], s4, 8);
        }
        // B staging: float4 loads (16 B/lane), transpose into Bs
#pragma unroll
        for (int p = 0; p < 4; ++p) {
            const int kk = (t >> 4) + 16 * p;
            const int c4 = (t & 15) * 4;
            const float4 v = *(const float4*)(W + (size_t)(kb + kk) * ldw + n0 + c4);
            Bs[c4 + 0][kk] = f2bs(v.x);
            Bs[c4 + 1][kk] = f2bs(v.y);
            Bs[c4 + 2][kk] = f2bs(v.z);
            Bs[c4 + 3][kk] = f2bs(v.w);
        }
        __syncthreads();
#pragma unroll
        for (int ks = 0; ks < 2; ++ks) {
            const short8 bf = *(const short8*)&Bs[w * 16 + l15][ks * 32 + quad * 8];
#pragma unroll
            for (int mi = 0; mi < 2; ++mi) {
                const short8 af = *(const short8*)&As[mi * 16 + l15][ks * 32 + quad * 8];
                acc[mi] = __builtin_amdgcn_mfma_f32_16x16x32_bf16(af, bf, acc[mi], 0, 0, 0);
            }
        }
        __syncthreads();
    }
    const int col = n0 + w * 16 + l15;
    if (Cf32) {
#pragma unroll
        for (int mi = 0; mi < 2; ++mi)
#pragma unroll
            for (int r = 0; r < 4; ++r) {
                const int row = m0 + mi * 16 + quad * 4 + r;
                if (atomicC) atomicAdd(&Cf32[(size_t)row * ldc + col], acc[mi][r]);
                else Cf32[(size_t)row * ldc + col] = acc[mi][r];
            }
    }
    if (BT) { // bf16 transposed store: BT[col][row]
#pragma unroll
        for (int mi = 0; mi < 2; ++mi) {
            unsigned short s4[4];
#pragma unroll
            for (int r = 0; r < 4; ++r) s4[r] = f2bs(acc[mi][r]);
            __builtin_memcpy(&BT[(size_t)col * NN + m0 + mi * 16 + quad * 4], s4, 8);
        }
    }
    if (sOut) { // head-projection partial dots (linear in acc, ksplit-safe)
        const float as = aSrc[col];
        const float ad = aDst[col];
        const int h = n0 >> 8;
#pragma unroll
        for (int mi = 0; mi < 2; ++mi)
#pragma unroll
            for (int r = 0; r < 4; ++r) {
                float sv = acc[mi][r] * as;
                float dv = acc[mi][r] * ad;
#pragma unroll
                for (int off = 1; off < 16; off <<= 1) {
                    sv += __shfl_xor(sv, off);
                    dv += __shfl_xor(dv, off);
                }
                if (l15 == 0) {
                    const int row = m0 + mi * 16 + quad * 4 + r;
                    atomicAdd(&sOut[row * HH + h], sv);
                    atomicAdd(&dOut[row * HH + h], dv);
                }
            }
    }
}

// ---------------- init out with bias (fc accumulates atomically into it)
__global__ void __launch_bounds__(256) k_bias(const float* __restrict__ fcb,
                                              float* __restrict__ out) {
    const int i = blockIdx.x * 256 + threadIdx.x;
    out[i] = fcb[i & (DE - 1)];
}

// ---------------- MFMA GAT: factorized-exp softmax + P@W + ELU + store + pool dot
// grid (b,h,it) = 64*8*4 blocks, 512 thr (8 waves). Block: rows i0..i0+63, head h.
__global__ void __launch_bounds__(512, 4) k_gat(const unsigned short* __restrict__ WhLbT,
                                                const float* __restrict__ WhV,
                                                const float* __restrict__ srcL,
                                                const float* __restrict__ dstL,
                                                const float* __restrict__ srcV,
                                                const float* __restrict__ dstV,
                                                const float* __restrict__ adj,
                                                const float* __restrict__ pool_q,
                                                bf16* __restrict__ outb,
                                                float* __restrict__ ps) {
    const int bid = blockIdx.x;
    const int it = bid & 3;
    const int h  = (bid >> 2) & 7;
    const int b  = bid >> 5;
    const int i0 = it * 64;
    const int t = threadIdx.x;
    const int w = t >> 6;        // wave 0..7
    const int lane = t & 63;
    const int l15 = lane & 15, quad = lane >> 4;

    __shared__ __align__(16) unsigned short Pl[64][PSTRIDE]; // 33.8 KB
    __shared__ __align__(16) float dls2[2 * NN];             // (B_j, D_j) pairs
    __shared__ float slsA[64], slsC[64], slsTE[64], inv[64];

    const float c = srcV[b * HH + h] + dstV[b * HH + h];
    if (t < NN) {
        const float dl = dstL[t * HH + h];
        dls2[2 * t]     = __expf(dl);         // B_j
        dls2[2 * t + 1] = __expf(ALPHA * dl); // D_j
    }
    if (t < 64) {
        const float u = c + srcL[(i0 + t) * HH + h];
        slsA[t]  = __expf(u);
        slsC[t]  = __expf(ALPHA * u);
        slsTE[t] = __expf(-u);   // threshold: z>0 <=> B_j > TE_i
    }
    // preload epilogue constants early
    const int n0 = w * 32;
    float wv[2];
#pragma unroll
    for (int ni = 0; ni < 2; ++ni)
        wv[ni] = WhV[(size_t)b * DG + h * FF + n0 + ni * 16 + l15];
    __syncthreads();

    // ---- phase 1: masked exp via factorization (UNNORMALIZED; inv applied later)
    {
        const int g = lane >> 4, s = lane & 15;
#pragma unroll
        for (int rr = 0; rr < 2; ++rr) {
            const int iloc = w * 8 + rr * 4 + g;
            const int i = i0 + iloc;
            const float Ai = slsA[iloc], Ci = slsC[iloc], TEi = slsTE[iloc];
            float pr[16];
            float sum = 0.f;
#pragma unroll
            for (int jj = 0; jj < 8; ++jj) {
                const int j0 = 2 * s + 32 * jj;
                const float2 av = *(const float2*)(adj + (size_t)i * NN + j0);
                const float4 bd = *(const float4*)&dls2[2 * j0]; // B0,D0,B1,D1
                const bool g0 = bd.x > TEi;
                const bool g1 = bd.z > TEi;
                float p0 = (g0 ? Ai : Ci) * (g0 ? bd.x : bd.y);
                float p1 = (g1 ? Ai : Ci) * (g1 ? bd.z : bd.w);
                p0 = av.x > 0.f ? p0 : 0.f;
                p1 = av.y > 0.f ? p1 : 0.f;
                pr[2 * jj] = p0; pr[2 * jj + 1] = p1;
                sum += p0 + p1;
            }
#pragma unroll
            for (int off = 1; off < 16; off <<= 1) sum += __shfl_xor(sum, off);
            if (s == 0) inv[iloc] = 1.0f / sum;
#pragma unroll
            for (int jj = 0; jj < 8; ++jj) {
                const unsigned int pk =
                    ((unsigned int)f2bs(pr[2 * jj + 1]) << 16) | f2bs(pr[2 * jj]);
                *(unsigned int*)&Pl[iloc][2 * s + 32 * jj] = pk;
            }
        }
    }
    __syncthreads();

    // ---- phase 2: out[i0:+64, w*32:+32] = P~ @ WhL (mfma 16x16x32 bf16)
    f32x4 acc[4][2];
#pragma unroll
    for (int mi = 0; mi < 4; ++mi)
#pragma unroll
        for (int ni = 0; ni < 2; ++ni) acc[mi][ni] = (f32x4){0.f, 0.f, 0.f, 0.f};

    const unsigned short* wb = WhLbT + (size_t)(h * FF + n0 + l15) * NN + quad * 8;
    short8 bc0 = *(const short8*)(wb);
    short8 bc1 = *(const short8*)(wb + (size_t)16 * NN);
#pragma unroll
    for (int kc = 0; kc < 8; ++kc) {
        short8 bn0, bn1;
        if (kc < 7) {
            bn0 = *(const short8*)(wb + (kc + 1) * 32);
            bn1 = *(const short8*)(wb + (size_t)16 * NN + (kc + 1) * 32);
        }
        short8 a[4];
#pragma unroll
        for (int mi = 0; mi < 4; ++mi)
            a[mi] = *(const short8*)&Pl[mi * 16 + l15][kc * 32 + quad * 8];
#pragma unroll
        for (int mi = 0; mi < 4; ++mi)
            acc[mi][0] = __builtin_amdgcn_mfma_f32_16x16x32_bf16(a[mi], bc0, acc[mi][0], 0, 0, 0);
#pragma unroll
        for (int mi = 0; mi < 4; ++mi)
            acc[mi][1] = __builtin_amdgcn_mfma_f32_16x16x32_bf16(a[mi], bc1, acc[mi][1], 0, 0, 0);
        bc0 = bn0; bc1 = bn1;
    }
    __syncthreads(); // all waves done reading Pl

    // ---- epilogue A: normalize (×inv[row]) + WhV, ELU, bf16 -> Pl[row][f]
#pragma unroll
    for (int mi = 0; mi < 4; ++mi)
#pragma unroll
        for (int r = 0; r < 4; ++r) {
            const int row = mi * 16 + quad * 4 + r;
            const float ivr = inv[row];
#pragma unroll
            for (int ni = 0; ni < 2; ++ni) {
                float x = fmaf(acc[mi][ni][r], ivr, wv[ni]);
                x = x > 0.f ? x : (__expf(x) - 1.0f); // ELU
                Pl[row][n0 + ni * 16 + l15] = f2bs(x);
            }
        }
    __syncthreads();

    // ---- epilogue B: coalesced b128 stores + fused pool-score partial dot
    {
        const int r = t >> 3;        // 0..63
        const int cb = t & 7;        // 0..7
        const int f0 = cb * 32;
        const float* pq = pool_q + h * FF + f0;
        bf16* orow = outb + ((size_t)(b * NN + i0 + r)) * DG + h * FF + f0;
        float dot = 0.f;
#pragma unroll
        for (int i8 = 0; i8 < 4; ++i8) {
            const short8 v = *(const short8*)&Pl[r][f0 + 8 * i8];
            __builtin_memcpy(orow + 8 * i8, &v, 16);
            const float4 q0 = *(const float4*)(pq + 8 * i8);
            const float4 q1 = *(const float4*)(pq + 8 * i8 + 4);
            bf16 bb[8];
            __builtin_memcpy(bb, &v, 16);
            dot = fmaf(b2f(bb[0]), q0.x, dot);
            dot = fmaf(b2f(bb[1]), q0.y, dot);
            dot = fmaf(b2f(bb[2]), q0.z, dot);
            dot = fmaf(b2f(bb[3]), q0.w, dot);
            dot = fmaf(b2f(bb[4]), q1.x, dot);
            dot = fmaf(b2f(bb[5]), q1.y, dot);
            dot = fmaf(b2f(bb[6]), q1.z, dot);
            dot = fmaf(b2f(bb[7]), q1.w, dot);
        }
        dot += __shfl_xor(dot, 1);
        dot += __shfl_xor(dot, 2);
        dot += __shfl_xor(dot, 4);
        if (cb == 0) atomicAdd(&ps[b * NN + i0 + r], dot);
    }
}

// ---------------- pooled[b, dslice] = sum_n softmax(ps)[n] * out[b,n,dslice]
// grid (4 dtiles, 64 b), 256 thr; thread owns 2 consecutive d (u32 loads, coalesced),
// direct float2 store — no atomics, no pooled memset.
__global__ void __launch_bounds__(256) k_pool(const bf16* __restrict__ outb,
                                              const float* __restrict__ ps,
                                              float* __restrict__ pooled) {
    const int dt = blockIdx.x;  // 0..3
    const int b  = blockIdx.y;  // 0..63
    const int t  = threadIdx.x;
    __shared__ float wsm[NN];
    __shared__ float redm[4];
    __shared__ float reds[4];
    const float v = ps[b * NN + t];
    float m = v;
#pragma unroll
    for (int off = 32; off; off >>= 1) m = fmaxf(m, __shfl_xor(m, off));
    if ((t & 63) == 0) redm[t >> 6] = m;
    __syncthreads();
    m = fmaxf(fmaxf(redm[0], redm[1]), fmaxf(redm[2], redm[3]));
    const float e = __expf(v - m);
    float s = e;
#pragma unroll
    for (int off = 32; off; off >>= 1) s += __shfl_xor(s, off);
    if ((t & 63) == 0) reds[t >> 6] = s;
    __syncthreads();
    s = reds[0] + reds[1] + reds[2] + reds[3];
    wsm[t] = e / s;
    __syncthreads();
    const int d0 = dt * 512 + 2 * t;
    float a0 = 0.f, a1 = 0.f;
    const bf16* base = outb + (size_t)b * NN * DG + d0;
#pragma unroll 4
    for (int n = 0; n < NN; ++n) {
        const float wn = wsm[n];
        bf16 bb[2];
        *(unsigned int*)bb = *(const unsigned int*)(base + (size_t)n * DG);
        a0 = fmaf(wn, b2f(bb[0]), a0);
        a1 = fmaf(wn, b2f(bb[1]), a1);
    }
    pooled[(size_t)b * DG + d0]     = a0;
    pooled[(size_t)b * DG + d0 + 1] = a1;
}

extern "C" void kernel_launch(void* const* d_in, const int* in_sizes, int n_in,
                              void* d_out, int out_size, void* d_ws, size_t ws_size,
                              hipStream_t stream) {
    (void)in_sizes; (void)n_in; (void)out_size; (void)ws_size;
    const float* visual = (const float*)d_in[0];
    const float* labels = (const float*)d_in[1];
    const float* adj    = (const float*)d_in[2];
    const float* Wg     = (const float*)d_in[3];
    const float* a_src  = (const float*)d_in[4];
    const float* a_dst  = (const float*)d_in[5];
    const float* pool_q = (const float*)d_in[6];
    const float* fcW    = (const float*)d_in[7];
    const float* fcb    = (const float*)d_in[8];
    float* out = (float*)d_out;

    // workspace: [memset region: WhV srcL dstL srcV dstV ps] pooled outb WhLbT
    float* ws_f   = (float*)d_ws;
    float* WhV    = ws_f;                  // 64*2048
    float* srcL   = WhV + BB * DG;         // 256*8
    float* dstL   = srcL + NN * HH;        // 256*8
    float* srcV   = dstL + NN * HH;        // 64*8
    float* dstV   = srcV + BB * HH;        // 64*8
    float* ps     = dstV + BB * HH;        // 64*256
    float* pooled = ps + BB * NN;          // 64*2048
    bf16*  outb   = (bf16*)(pooled + BB * DG);        // 64*256*2048 bf16
    unsigned short* WhLbT = (unsigned short*)(outb + (size_t)BB * NN * DG); // 2048*256

    const size_t zero_floats = (size_t)BB * DG + NN * HH * 2 + BB * HH * 2 + BB * NN;
    hipMemsetAsync(WhV, 0, zero_floats * sizeof(float), stream);
    k_bias<<<BB * DE / 256, 256, 0, stream>>>(fcb, out);

    // WhL GEMM -> bf16 transposed WhLbT + srcL/dstL dots (no fp32 C)
    k_mgemm<<<dim3(DG / 64, NN / 32, 1), 256, 0, stream>>>(
        labels, D_LBL, Wg, DG, nullptr, 0, WhLbT, a_src, a_dst, srcL, dstL,
        D_LBL, D_LBL / 64, 0);
    // WhV GEMM -> fp32 WhV (atomic ksplit z=4) + srcV/dstV dots
    k_mgemm<<<dim3(DG / 64, BB / 32, 4), 256, 0, stream>>>(
        visual, D_VIS, Wg + (size_t)D_LBL * DG, DG, WhV, DG, nullptr,
        a_src, a_dst, srcV, dstV, 512, 8, 1);

    k_gat<<<BB * HH * 4, 512, 0, stream>>>(WhLbT, WhV, srcL, dstL, srcV, dstV,
                                           adj, pool_q, outb, ps);

    k_pool<<<dim3(4, BB), 256, 0, stream>>>(outb, ps, pooled);

    // out = pooled @ fcW + bias: ksplit atomic into bias-init out
    k_mgemm<<<dim3(DE / 64, BB / 32, 8), 256, 0, stream>>>(
        pooled, DG, fcW, DE, out, DE, nullptr, nullptr, nullptr, nullptr, nullptr,
        256, 4, 1);
}

// Round 10
// 218.376 us; speedup vs baseline: 1.2330x; 1.1264x over previous
//
#include <hip/hip_runtime.h>
#include <hip/hip_bf16.h>
#include <math.h>

#define BB 64
#define NN 256
#define D_VIS 2048
#define D_LBL 512
#define HH 8
#define FF 256
#define DG 2048   // D_GAT = H*F
#define DE 512    // D_EMB
#define ALPHA 0.2f
#define PSTRIDE 264  // Pl row stride in shorts (256 + 8 pad)

using bf16 = __hip_bfloat16;
using short8 = __attribute__((ext_vector_type(8))) short;
using f32x4  = __attribute__((ext_vector_type(4))) float;
__device__ __forceinline__ float b2f(bf16 x) { return __bfloat162float(x); }
__device__ __forceinline__ unsigned short f2bs(float x) {
    bf16 h = __float2bfloat16(x);
    unsigned short u;
    __builtin_memcpy(&u, &h, 2);
    return u;
}

// ---------------- fused Wh GEMM: one dispatch for WhL and WhV.
// grid (32, 16): y<8 -> WhL row-tile y (K=512, BT+dots out);
//                y>=8 -> WhV row-tile (y-8)&1, K-slice (y-8)>>1 (direct store slice).
__global__ void __launch_bounds__(256) k_wh(const float* __restrict__ labels,
                                            const float* __restrict__ visual,
                                            const float* __restrict__ Wg,
                                            unsigned short* __restrict__ WhLbT,
                                            float* __restrict__ WhVz,
                                            const float* __restrict__ aSrc,
                                            const float* __restrict__ aDst,
                                            float* __restrict__ srcL,
                                            float* __restrict__ dstL,
                                            float* __restrict__ srcV,
                                            float* __restrict__ dstV) {
    __shared__ unsigned short As[32][72];
    __shared__ unsigned short Bs[64][72];
    const int t = threadIdx.x;
    const int w = t >> 6;
    const int lane = t & 63;
    const int l15 = lane & 15, quad = lane >> 4;
    const int n0 = blockIdx.x * 64;
    const int y = blockIdx.y;
    const bool isL = (y < 8);
    const int q = y - 8;
    const int m0  = isL ? y * 32 : (q & 1) * 32;
    const int z   = isL ? 0 : (q >> 1);
    const int kb0 = z * 512;
    const float* A = isL ? labels : visual;
    const int lda  = isL ? D_LBL : D_VIS;
    const float* Wb = Wg + (isL ? 0 : (size_t)D_LBL * DG);

    f32x4 acc[2];
    acc[0] = (f32x4){0.f, 0.f, 0.f, 0.f};
    acc[1] = (f32x4){0.f, 0.f, 0.f, 0.f};

    for (int kc = 0; kc < 8; ++kc) {
        const int kb = kb0 + kc * 64;
#pragma unroll
        for (int p = 0; p < 2; ++p) {
            const int idx = t + 256 * p;
            const int r = idx >> 4, q4 = idx & 15;
            const float4 v = *(const float4*)(A + (size_t)(m0 + r) * lda + kb + 4 * q4);
            unsigned short s4[4] = {f2bs(v.x), f2bs(v.y), f2bs(v.z), f2bs(v.w)};
            __builtin_memcpy(&As[r][4 * q4], s4, 8);
        }
#pragma unroll
        for (int p = 0; p < 4; ++p) {
            const int kk = (t >> 4) + 16 * p;
            const int c4 = (t & 15) * 4;
            const float4 v = *(const float4*)(Wb + (size_t)(kb + kk) * DG + n0 + c4);
            Bs[c4 + 0][kk] = f2bs(v.x);
            Bs[c4 + 1][kk] = f2bs(v.y);
            Bs[c4 + 2][kk] = f2bs(v.z);
            Bs[c4 + 3][kk] = f2bs(v.w);
        }
        __syncthreads();
#pragma unroll
        for (int ks = 0; ks < 2; ++ks) {
            const short8 bf = *(const short8*)&Bs[w * 16 + l15][ks * 32 + quad * 8];
#pragma unroll
            for (int mi = 0; mi < 2; ++mi) {
                const short8 af = *(const short8*)&As[mi * 16 + l15][ks * 32 + quad * 8];
                acc[mi] = __builtin_amdgcn_mfma_f32_16x16x32_bf16(af, bf, acc[mi], 0, 0, 0);
            }
        }
        __syncthreads();
    }
    const int col = n0 + w * 16 + l15;
    const int h = col >> 8;
    if (isL) {
        // bf16 transposed store WhLbT[col][row]
#pragma unroll
        for (int mi = 0; mi < 2; ++mi) {
            unsigned short s4[4];
#pragma unroll
            for (int r = 0; r < 4; ++r) s4[r] = f2bs(acc[mi][r]);
            __builtin_memcpy(&WhLbT[(size_t)col * NN + m0 + mi * 16 + quad * 4], s4, 8);
        }
        const float as = aSrc[col], ad = aDst[col];
#pragma unroll
        for (int mi = 0; mi < 2; ++mi)
#pragma unroll
            for (int r = 0; r < 4; ++r) {
                float sv = acc[mi][r] * as;
                float dv = acc[mi][r] * ad;
#pragma unroll
                for (int off = 1; off < 16; off <<= 1) {
                    sv += __shfl_xor(sv, off);
                    dv += __shfl_xor(dv, off);
                }
                if (l15 == 0) {
                    const int row = m0 + mi * 16 + quad * 4 + r;
                    atomicAdd(&srcL[row * HH + h], sv);
                    atomicAdd(&dstL[row * HH + h], dv);
                }
            }
    } else {
        float* Wv = WhVz + (size_t)z * BB * DG;
#pragma unroll
        for (int mi = 0; mi < 2; ++mi)
#pragma unroll
            for (int r = 0; r < 4; ++r)
                Wv[(size_t)(m0 + mi * 16 + quad * 4 + r) * DG + col] = acc[mi][r];
        const float as = aSrc[col], ad = aDst[col];
#pragma unroll
        for (int mi = 0; mi < 2; ++mi)
#pragma unroll
            for (int r = 0; r < 4; ++r) {
                float sv = acc[mi][r] * as;
                float dv = acc[mi][r] * ad;
#pragma unroll
                for (int off = 1; off < 16; off <<= 1) {
                    sv += __shfl_xor(sv, off);
                    dv += __shfl_xor(dv, off);
                }
                if (l15 == 0) {
                    const int row = m0 + mi * 16 + quad * 4 + r;
                    atomicAdd(&srcV[row * HH + h], sv);
                    atomicAdd(&dstV[row * HH + h], dv);
                }
            }
    }
}

// ---------------- fc GEMM (unchanged path): atomic ksplit into bias-init out
__global__ void __launch_bounds__(256) k_mgemm(const float* __restrict__ A, int lda,
                                               const float* __restrict__ W, int ldw,
                                               float* __restrict__ C, int ldc,
                                               int kSlice, int kIters) {
    __shared__ unsigned short As[32][72];
    __shared__ unsigned short Bs[64][72];
    const int t = threadIdx.x;
    const int w = t >> 6;
    const int lane = t & 63;
    const int l15 = lane & 15, quad = lane >> 4;
    const int n0 = blockIdx.x * 64;
    const int m0 = blockIdx.y * 32;
    const int kb0 = blockIdx.z * kSlice;
    f32x4 acc[2];
    acc[0] = (f32x4){0.f, 0.f, 0.f, 0.f};
    acc[1] = (f32x4){0.f, 0.f, 0.f, 0.f};
    for (int kc = 0; kc < kIters; ++kc) {
        const int kb = kb0 + kc * 64;
#pragma unroll
        for (int p = 0; p < 2; ++p) {
            const int idx = t + 256 * p;
            const int r = idx >> 4, q4 = idx & 15;
            const float4 v = *(const float4*)(A + (size_t)(m0 + r) * lda + kb + 4 * q4);
            unsigned short s4[4] = {f2bs(v.x), f2bs(v.y), f2bs(v.z), f2bs(v.w)};
            __builtin_memcpy(&As[r][4 * q4], s4, 8);
        }
#pragma unroll
        for (int p = 0; p < 4; ++p) {
            const int kk = (t >> 4) + 16 * p;
            const int c4 = (t & 15) * 4;
            const float4 v = *(const float4*)(W + (size_t)(kb + kk) * ldw + n0 + c4);
            Bs[c4 + 0][kk] = f2bs(v.x);
            Bs[c4 + 1][kk] = f2bs(v.y);
            Bs[c4 + 2][kk] = f2bs(v.z);
            Bs[c4 + 3][kk] = f2bs(v.w);
        }
        __syncthreads();
#pragma unroll
        for (int ks = 0; ks < 2; ++ks) {
            const short8 bf = *(const short8*)&Bs[w * 16 + l15][ks * 32 + quad * 8];
#pragma unroll
            for (int mi = 0; mi < 2; ++mi) {
                const short8 af = *(const short8*)&As[mi * 16 + l15][ks * 32 + quad * 8];
                acc[mi] = __builtin_amdgcn_mfma_f32_16x16x32_bf16(af, bf, acc[mi], 0, 0, 0);
            }
        }
        __syncthreads();
    }
    const int col = n0 + w * 16 + l15;
#pragma unroll
    for (int mi = 0; mi < 2; ++mi)
#pragma unroll
        for (int r = 0; r < 4; ++r)
            atomicAdd(&C[(size_t)(m0 + mi * 16 + quad * 4 + r) * ldc + col], acc[mi][r]);
}

// ---------------- MFMA GAT: factorized softmax + P@W + register epilogue (2 barriers)
// grid (b,h,it) = 64*8*4 blocks, 512 thr (8 waves).
__global__ void __launch_bounds__(512, 4) k_gat(const unsigned short* __restrict__ WhLbT,
                                                const float* __restrict__ WhVz,
                                                const float* __restrict__ srcL,
                                                const float* __restrict__ dstL,
                                                const float* __restrict__ srcV,
                                                const float* __restrict__ dstV,
                                                const float* __restrict__ adj,
                                                const float* __restrict__ pool_q,
                                                bf16* __restrict__ outb,
                                                float* __restrict__ ps_p) {
    const int bid = blockIdx.x;
    const int it = bid & 3;
    const int h  = (bid >> 2) & 7;
    const int b  = bid >> 5;
    const int i0 = it * 64;
    const int t = threadIdx.x;
    const int w = t >> 6;
    const int lane = t & 63;
    const int l15 = lane & 15, quad = lane >> 4;

    __shared__ __align__(16) unsigned short Pl[64][PSTRIDE]; // 33.8 KB
    __shared__ __align__(16) float dls2[2 * NN];
    __shared__ float slsA[64], slsC[64], slsTE[64], inv[64];

    const float c = srcV[b * HH + h] + dstV[b * HH + h];
    if (t < NN) {
        const float dl = dstL[t * HH + h];
        dls2[2 * t]     = __expf(dl);
        dls2[2 * t + 1] = __expf(ALPHA * dl);
    }
    if (t < 64) {
        const float u = c + srcL[(i0 + t) * HH + h];
        slsA[t]  = __expf(u);
        slsC[t]  = __expf(ALPHA * u);
        slsTE[t] = __expf(-u);
    }
    const int n0 = w * 32;
    float wv[2] = {0.f, 0.f};
#pragma unroll
    for (int z = 0; z < 4; ++z)
#pragma unroll
        for (int ni = 0; ni < 2; ++ni)
            wv[ni] += WhVz[(size_t)z * BB * DG + (size_t)b * DG + h * FF + n0 + ni * 16 + l15];
    __syncthreads();

    // ---- phase 1: masked exp via factorization (unnormalized)
    {
        const int g = lane >> 4, s = lane & 15;
#pragma unroll
        for (int rr = 0; rr < 2; ++rr) {
            const int iloc = w * 8 + rr * 4 + g;
            const int i = i0 + iloc;
            const float Ai = slsA[iloc], Ci = slsC[iloc], TEi = slsTE[iloc];
            float pr[16];
            float sum = 0.f;
#pragma unroll
            for (int jj = 0; jj < 8; ++jj) {
                const int j0 = 2 * s + 32 * jj;
                const float2 av = *(const float2*)(adj + (size_t)i * NN + j0);
                const float4 bd = *(const float4*)&dls2[2 * j0];
                const bool g0 = bd.x > TEi;
                const bool g1 = bd.z > TEi;
                float p0 = (g0 ? Ai : Ci) * (g0 ? bd.x : bd.y);
                float p1 = (g1 ? Ai : Ci) * (g1 ? bd.z : bd.w);
                p0 = av.x > 0.f ? p0 : 0.f;
                p1 = av.y > 0.f ? p1 : 0.f;
                pr[2 * jj] = p0; pr[2 * jj + 1] = p1;
                sum += p0 + p1;
            }
#pragma unroll
            for (int off = 1; off < 16; off <<= 1) sum += __shfl_xor(sum, off);
            if (s == 0) inv[iloc] = 1.0f / sum;
#pragma unroll
            for (int jj = 0; jj < 8; ++jj) {
                const unsigned int pk =
                    ((unsigned int)f2bs(pr[2 * jj + 1]) << 16) | f2bs(pr[2 * jj]);
                *(unsigned int*)&Pl[iloc][2 * s + 32 * jj] = pk;
            }
        }
    }
    __syncthreads();

    // ---- phase 2: out[i0:+64, w*32:+32] = P~ @ WhL (mfma 16x16x32 bf16)
    f32x4 acc[4][2];
#pragma unroll
    for (int mi = 0; mi < 4; ++mi)
#pragma unroll
        for (int ni = 0; ni < 2; ++ni) acc[mi][ni] = (f32x4){0.f, 0.f, 0.f, 0.f};

    const unsigned short* wb = WhLbT + (size_t)(h * FF + n0 + l15) * NN + quad * 8;
    short8 bc0 = *(const short8*)(wb);
    short8 bc1 = *(const short8*)(wb + (size_t)16 * NN);
#pragma unroll
    for (int kc = 0; kc < 8; ++kc) {
        short8 bn0, bn1;
        if (kc < 7) {
            bn0 = *(const short8*)(wb + (kc + 1) * 32);
            bn1 = *(const short8*)(wb + (size_t)16 * NN + (kc + 1) * 32);
        }
        short8 a[4];
#pragma unroll
        for (int mi = 0; mi < 4; ++mi)
            a[mi] = *(const short8*)&Pl[mi * 16 + l15][kc * 32 + quad * 8];
#pragma unroll
        for (int mi = 0; mi < 4; ++mi)
            acc[mi][0] = __builtin_amdgcn_mfma_f32_16x16x32_bf16(a[mi], bc0, acc[mi][0], 0, 0, 0);
#pragma unroll
        for (int mi = 0; mi < 4; ++mi)
            acc[mi][1] = __builtin_amdgcn_mfma_f32_16x16x32_bf16(a[mi], bc1, acc[mi][1], 0, 0, 0);
        bc0 = bn0; bc1 = bn1;
    }

    // ---- register epilogue: normalize + WhV, ELU, direct bf16 store + pool dot
    const float pqv0 = pool_q[h * FF + n0 + l15];
    const float pqv1 = pool_q[h * FF + n0 + 16 + l15];
    float* psrow = ps_p + (size_t)(h * 8 + w) * BB * NN + (size_t)b * NN + i0;
#pragma unroll
    for (int mi = 0; mi < 4; ++mi)
#pragma unroll
        for (int r = 0; r < 4; ++r) {
            const int row = mi * 16 + quad * 4 + r;
            const float ivr = inv[row];
            bf16* orow = outb + ((size_t)(b * NN + i0 + row)) * DG + h * FF + n0;
            float x0 = fmaf(acc[mi][0][r], ivr, wv[0]);
            float x1 = fmaf(acc[mi][1][r], ivr, wv[1]);
            x0 = x0 > 0.f ? x0 : (__expf(x0) - 1.0f);
            x1 = x1 > 0.f ? x1 : (__expf(x1) - 1.0f);
            orow[l15]      = __float2bfloat16(x0);
            orow[16 + l15] = __float2bfloat16(x1);
            float dot = fmaf(x0, pqv0, x1 * pqv1);
#pragma unroll
            for (int off = 1; off < 16; off <<= 1) dot += __shfl_xor(dot, off);
            if (l15 == 0) psrow[row] = dot;
        }
}

// ---------------- k_pool: ps_p reduce + softmax + weighted sum; also bias-inits out
__global__ void __launch_bounds__(256) k_pool(const bf16* __restrict__ outb,
                                              const float* __restrict__ ps_p,
                                              float* __restrict__ pooled,
                                              const float* __restrict__ fcb,
                                              float* __restrict__ out) {
    const int dt = blockIdx.x;  // 0..3
    const int b  = blockIdx.y;  // 0..63
    const int t  = threadIdx.x;
    if (dt < 2) out[b * DE + dt * 256 + t] = fcb[dt * 256 + t];
    __shared__ float wsm[NN];
    __shared__ float redm[4];
    __shared__ float reds[4];
    float v = 0.f;
#pragma unroll 8
    for (int s = 0; s < 64; ++s)
        v += ps_p[(size_t)s * BB * NN + (size_t)b * NN + t];
    float m = v;
#pragma unroll
    for (int off = 32; off; off >>= 1) m = fmaxf(m, __shfl_xor(m, off));
    if ((t & 63) == 0) redm[t >> 6] = m;
    __syncthreads();
    m = fmaxf(fmaxf(redm[0], redm[1]), fmaxf(redm[2], redm[3]));
    const float e = __expf(v - m);
    float s = e;
#pragma unroll
    for (int off = 32; off; off >>= 1) s += __shfl_xor(s, off);
    if ((t & 63) == 0) reds[t >> 6] = s;
    __syncthreads();
    s = reds[0] + reds[1] + reds[2] + reds[3];
    wsm[t] = e / s;
    __syncthreads();
    const int d0 = dt * 512 + 2 * t;
    float a0 = 0.f, a1 = 0.f;
    const bf16* base = outb + (size_t)b * NN * DG + d0;
#pragma unroll 4
    for (int n = 0; n < NN; ++n) {
        const float wn = wsm[n];
        bf16 bb[2];
        *(unsigned int*)bb = *(const unsigned int*)(base + (size_t)n * DG);
        a0 = fmaf(wn, b2f(bb[0]), a0);
        a1 = fmaf(wn, b2f(bb[1]), a1);
    }
    pooled[(size_t)b * DG + d0]     = a0;
    pooled[(size_t)b * DG + d0 + 1] = a1;
}

extern "C" void kernel_launch(void* const* d_in, const int* in_sizes, int n_in,
                              void* d_out, int out_size, void* d_ws, size_t ws_size,
                              hipStream_t stream) {
    (void)in_sizes; (void)n_in; (void)out_size; (void)ws_size;
    const float* visual = (const float*)d_in[0];
    const float* labels = (const float*)d_in[1];
    const float* adj    = (const float*)d_in[2];
    const float* Wg     = (const float*)d_in[3];
    const float* a_src  = (const float*)d_in[4];
    const float* a_dst  = (const float*)d_in[5];
    const float* pool_q = (const float*)d_in[6];
    const float* fcW    = (const float*)d_in[7];
    const float* fcb    = (const float*)d_in[8];
    float* out = (float*)d_out;

    float* ws_f   = (float*)d_ws;
    float* WhVz   = ws_f;                       // 4*64*2048
    float* srcL   = WhVz + 4 * BB * DG;         // 256*8  -- memset region start
    float* dstL   = srcL + NN * HH;             // 256*8
    float* srcV   = dstL + NN * HH;             // 64*8
    float* dstV   = srcV + BB * HH;             // 64*8   -- memset region end
    float* ps_p   = dstV + BB * HH;             // 64*64*256
    float* pooled = ps_p + 64 * BB * NN;        // 64*2048
    bf16*  outb   = (bf16*)(pooled + BB * DG);  // 64*256*2048 bf16
    unsigned short* WhLbT = (unsigned short*)(outb + (size_t)BB * NN * DG); // 2048*256

    hipMemsetAsync(srcL, 0, (NN * HH * 2 + BB * HH * 2) * sizeof(float), stream);

    k_wh<<<dim3(DG / 64, 16), 256, 0, stream>>>(labels, visual, Wg, WhLbT, WhVz,
                                                a_src, a_dst, srcL, dstL, srcV, dstV);

    k_gat<<<BB * HH * 4, 512, 0, stream>>>(WhLbT, WhVz, srcL, dstL, srcV, dstV,
                                           adj, pool_q, outb, ps_p);

    k_pool<<<dim3(4, BB), 256, 0, stream>>>(outb, ps_p, pooled, fcb, out);

    k_mgemm<<<dim3(DE / 64, BB / 32, 8), 256, 0, stream>>>(
        pooled, DG, fcW, DE, out, DE, 256, 4);
}